// Round 1
// 442.777 us; speedup vs baseline: 1.0866x; 1.0866x over previous
//
#include <hip/hip_runtime.h>
#include <math.h>

#define BB 8
#define MM 64
#define DD 256
#define NP 16384
#define EPSF 1e-7f
#define NEPS 1e-12f

// ws layout (float offsets)
#define OFF_AT   0u          // At   [B][D][M]  alpha * normalized c, transposed
#define OFF_VC   131072u     // vc   [B][M][D]
#define OFF_AGG  262144u     // agg  [B][M][D]
#define OFF_ASUM 393216u     // asum [B][M]
#define OFF_ASNT 393728u     // asnT [B][N][M]  assignment transposed
#define OFF_WCT  8782336u    // Wc^T [D][D]
#define OFF_WVT  8847872u    // Wv^T [D][D]
#define OFF_PART 8913408u    // part [64][B][M][D] split-K partials (32 MB)

typedef __attribute__((ext_vector_type(8))) short bf16x8;
typedef __attribute__((ext_vector_type(4))) float f32x4;

// ---------------- K0: transpose Wc, Wv ----------------
__global__ __launch_bounds__(256) void k0_transpose(
    const float* __restrict__ Wc, const float* __restrict__ Wv,
    float* __restrict__ ws)
{
    __shared__ float tls[32][33];
    int which = blockIdx.z;
    const float* W = which ? Wv : Wc;
    float* Wt = ws + (which ? OFF_WVT : OFF_WCT);
    int j0 = blockIdx.x * 32, k0 = blockIdx.y * 32;
    int c = threadIdx.x & 31, r0 = threadIdx.x >> 5;
    #pragma unroll
    for (int rr = r0; rr < 32; rr += 8)
        tls[rr][c] = W[(size_t)(j0 + rr) * DD + k0 + c];
    __syncthreads();
    #pragma unroll
    for (int rr = r0; rr < 32; rr += 8)
        Wt[(size_t)(k0 + rr) * DD + j0 + c] = tls[c][rr];
}

// ---------------- K1: c / vc prep ----------------
__global__ __launch_bounds__(256) void k1_prep(
    const float* __restrict__ clusters, const float* __restrict__ vclusters,
    const float* __restrict__ alpha, const float* __restrict__ cbias,
    const float* __restrict__ bc, const float* __restrict__ vcbias,
    const float* __restrict__ bvv, float* __restrict__ ws)
{
    __shared__ float s_in[16][256];
    __shared__ float wt_s[32][256];
    __shared__ float s_out[16][260];
    __shared__ float s_scale[16];

    int t = threadIdx.x;
    int mt = blockIdx.x, b = blockIdx.y, which = blockIdx.z;
    int m0 = mt * 16;
    const float* inp   = which ? vclusters : clusters;
    const float* ibias = which ? vcbias : cbias;
    const float* obias = which ? bvv : bc;
    const float* Wt = ws + (which ? OFF_WVT : OFF_WCT);

    #pragma unroll
    for (int i = 0; i < 4; i++) {
        int e = i * 1024 + t * 4;
        int r = e >> 8, c = e & 255;
        float4 a  = *(const float4*)&inp[((size_t)(b * MM + m0 + r)) * DD + c];
        float4 bb = *(const float4*)&ibias[(size_t)(m0 + r) * DD + c];
        a.x += bb.x; a.y += bb.y; a.z += bb.z; a.w += bb.w;
        *(float4*)&s_in[r][c] = a;
    }

    int tm = t >> 5, tt = t & 31;
    float acc[2][8];
    #pragma unroll
    for (int i = 0; i < 2; i++)
        #pragma unroll
        for (int q = 0; q < 8; q++) acc[i][q] = 0.f;

    for (int k0 = 0; k0 < DD; k0 += 32) {
        __syncthreads();
        #pragma unroll
        for (int i = 0; i < 8; i++) {
            int e = i * 1024 + t * 4;
            int kd = e >> 8, c = e & 255;
            *(float4*)&wt_s[kd][c] = *(const float4*)&Wt[(size_t)(k0 + kd) * DD + c];
        }
        __syncthreads();
        #pragma unroll
        for (int kd = 0; kd < 32; kd++) {
            float a0 = s_in[tm][k0 + kd];
            float a1 = s_in[tm + 8][k0 + kd];
            float4 b0 = *(const float4*)&wt_s[kd][tt * 4];
            float4 b1 = *(const float4*)&wt_s[kd][128 + tt * 4];
            float bq[8] = {b0.x, b0.y, b0.z, b0.w, b1.x, b1.y, b1.z, b1.w};
            #pragma unroll
            for (int q = 0; q < 8; q++) { acc[0][q] += a0 * bq[q]; acc[1][q] += a1 * bq[q]; }
        }
    }

    #pragma unroll
    for (int q = 0; q < 8; q++) {
        int col = (q < 4) ? (tt * 4 + q) : (128 + tt * 4 + (q - 4));
        float ob = obias[col];
        #pragma unroll
        for (int i = 0; i < 2; i++) {
            int r = tm + i * 8;
            float x = acc[i][q] + ob;
            float s = x / (1.f + __expf(-x));   // silu
            s_out[r][col] = s;
        }
    }
    __syncthreads();

    if (which == 0) {
        if (t < 16) {
            float ss = 0.f;
            for (int j = 0; j < 256; j++) { float v = s_out[t][j]; ss += v * v; }
            s_scale[t] = alpha[m0 + t] / fmaxf(sqrtf(ss), NEPS);
        }
        __syncthreads();
        float* At = ws + OFF_AT + (size_t)b * DD * MM + (size_t)t * MM + m0;
        #pragma unroll
        for (int i = 0; i < 16; i++) At[i] = s_out[i][t] * s_scale[i];
    } else {
        float* vc = ws + OFF_VC + (size_t)(b * MM + m0) * DD;
        #pragma unroll
        for (int i = 0; i < 16; i++) vc[(size_t)i * DD + t] = s_out[i][t];
    }
}

// ---------------- K3 (MFMA bf16x3): sim + softmax + asnT + asum ----------------
// 512 threads = 8 waves; wave w owns 64m x 32n; tile per block: 64m x 256n.
// B (points) fragments loaded straight from global in MFMA lane layout
// -> no barriers in the main loop. A split hi/lo in LDS once per block.
__global__ __launch_bounds__(512, 4) void k3_sim(
    const float* __restrict__ points, const float* __restrict__ beta,
    float* __restrict__ ws)
{
    // row stride 264 shorts = 528 B: 16B-aligned, bank-balanced for b128 frag reads
    __shared__ __align__(16) unsigned short Ah[64][264];
    __shared__ __align__(16) unsigned short Al[64][264];
    __shared__ float s_red[8][64];
    __shared__ float s_beta[64];

    int t = threadIdx.x;
    int b = blockIdx.y;
    int n0 = blockIdx.x * 256;
    int w = t >> 6;          // wave id -> n-group of 32
    int l = t & 63;
    int c = l & 15;          // frag col (A row / B col / D col)
    int g = l >> 4;          // k-quarter (8 elems each), D row group

    const float* At = ws + OFF_AT + (size_t)b * DD * MM;   // [256 d][64 m]

    if (t < 64) s_beta[t] = beta[t];

    // prologue: split A into hi/lo bf16 (truncation -> lo exact in fp32)
    #pragma unroll
    for (int i = 0; i < 8; i++) {
        int f = i * 512 + t;
        int d = f >> 4, m4 = (f & 15) * 4;
        float4 v = *(const float4*)&At[(size_t)d * MM + m4];
        float xs[4] = {v.x, v.y, v.z, v.w};
        #pragma unroll
        for (int j = 0; j < 4; j++) {
            unsigned u = __float_as_uint(xs[j]);
            float lof = xs[j] - __uint_as_float(u & 0xffff0000u);
            Ah[m4 + j][d] = (unsigned short)(u >> 16);
            Al[m4 + j][d] = (unsigned short)(__float_as_uint(lof) >> 16);
        }
    }
    __syncthreads();

    const float* pb = points + (size_t)b * DD * NP;
    const float* pbase = pb + n0 + w * 32 + c;

    f32x4 acc[4][2];
    #pragma unroll
    for (int am = 0; am < 4; am++)
        #pragma unroll
        for (int an = 0; an < 2; an++)
            acc[am][an] = (f32x4){0.f, 0.f, 0.f, 0.f};

    float sq[2] = {0.f, 0.f};
    float cur[2][8], nxt[2][8];

    #pragma unroll
    for (int an = 0; an < 2; an++)
        #pragma unroll
        for (int i = 0; i < 8; i++)
            cur[an][i] = pbase[(size_t)(g * 8 + i) * NP + an * 16];

    #pragma unroll
    for (int kc = 0; kc < 8; kc++) {
        if (kc < 7) {
            #pragma unroll
            for (int an = 0; an < 2; an++)
                #pragma unroll
                for (int i = 0; i < 8; i++)
                    nxt[an][i] = pbase[(size_t)((kc + 1) * 32 + g * 8 + i) * NP + an * 16];
        }
        union { bf16x8 v; unsigned u[4]; } bh[2], bl[2];
        #pragma unroll
        for (int an = 0; an < 2; an++) {
            #pragma unroll
            for (int p = 0; p < 4; p++) {
                float x0 = cur[an][2 * p], x1 = cur[an][2 * p + 1];
                unsigned u0 = __float_as_uint(x0), u1 = __float_as_uint(x1);
                float l0f = x0 - __uint_as_float(u0 & 0xffff0000u);
                float l1f = x1 - __uint_as_float(u1 & 0xffff0000u);
                bh[an].u[p] = (u0 >> 16) | (u1 & 0xffff0000u);
                bl[an].u[p] = (__float_as_uint(l0f) >> 16) | (__float_as_uint(l1f) & 0xffff0000u);
            }
            #pragma unroll
            for (int i = 0; i < 8; i++) sq[an] += cur[an][i] * cur[an][i];
        }
        #pragma unroll
        for (int am = 0; am < 4; am++) {
            bf16x8 ah = *(const bf16x8*)&Ah[am * 16 + c][kc * 32 + g * 8];
            bf16x8 al = *(const bf16x8*)&Al[am * 16 + c][kc * 32 + g * 8];
            #pragma unroll
            for (int an = 0; an < 2; an++) {
                acc[am][an] = __builtin_amdgcn_mfma_f32_16x16x32_bf16(ah, bh[an].v, acc[am][an], 0, 0, 0);
                acc[am][an] = __builtin_amdgcn_mfma_f32_16x16x32_bf16(ah, bl[an].v, acc[am][an], 0, 0, 0);
                acc[am][an] = __builtin_amdgcn_mfma_f32_16x16x32_bf16(al, bh[an].v, acc[am][an], 0, 0, 0);
            }
        }
        if (kc < 7) {
            #pragma unroll
            for (int an = 0; an < 2; an++)
                #pragma unroll
                for (int i = 0; i < 8; i++) cur[an][i] = nxt[an][i];
        }
    }

    // column 1/||p||: reduce per-lane sumsq over k-quarters (g)
    float pinv2[2], cmax[2], csum[2];
    #pragma unroll
    for (int an = 0; an < 2; an++) {
        float s = sq[an];
        s += __shfl_xor(s, 16);
        s += __shfl_xor(s, 32);
        pinv2[an] = 1.f / fmaxf(sqrtf(s), NEPS);
        cmax[an] = -1e30f;
    }

    // sim = acc*pinv + beta; softmax over m (in-lane 16 + 2 shuffles)
    #pragma unroll
    for (int am = 0; am < 4; am++)
        #pragma unroll
        for (int an = 0; an < 2; an++)
            #pragma unroll
            for (int r = 0; r < 4; r++) {
                float s = acc[am][an][r] * pinv2[an] + s_beta[am * 16 + g * 4 + r];
                acc[am][an][r] = s;
                cmax[an] = fmaxf(cmax[an], s);
            }
    #pragma unroll
    for (int an = 0; an < 2; an++) {
        cmax[an] = fmaxf(cmax[an], __shfl_xor(cmax[an], 16));
        cmax[an] = fmaxf(cmax[an], __shfl_xor(cmax[an], 32));
        csum[an] = 0.f;
    }
    #pragma unroll
    for (int am = 0; am < 4; am++)
        #pragma unroll
        for (int an = 0; an < 2; an++)
            #pragma unroll
            for (int r = 0; r < 4; r++) {
                float e = __expf(acc[am][an][r] - cmax[an]);
                acc[am][an][r] = e;
                csum[an] += e;
            }
    #pragma unroll
    for (int an = 0; an < 2; an++) {
        float s = csum[an];
        s += __shfl_xor(s, 16);
        s += __shfl_xor(s, 32);
        csum[an] = 1.f / s;
    }

    float msum[4][4];
    #pragma unroll
    for (int am = 0; am < 4; am++)
        #pragma unroll
        for (int r = 0; r < 4; r++) msum[am][r] = 0.f;

    float* asnT = ws + OFF_ASNT + (size_t)b * NP * MM;
    int ncol = n0 + w * 32 + c;
    #pragma unroll
    for (int am = 0; am < 4; am++)
        #pragma unroll
        for (int an = 0; an < 2; an++)
            #pragma unroll
            for (int r = 0; r < 4; r++) {
                float v = acc[am][an][r] * csum[an];
                asnT[(size_t)(ncol + an * 16) * MM + am * 16 + g * 4 + r] = v;
                msum[am][r] += v;
            }

    // asum: reduce over n within wave (c bits), then cross-wave via LDS
    #pragma unroll
    for (int am = 0; am < 4; am++)
        #pragma unroll
        for (int r = 0; r < 4; r++) {
            float s = msum[am][r];
            s += __shfl_xor(s, 1);
            s += __shfl_xor(s, 2);
            s += __shfl_xor(s, 4);
            s += __shfl_xor(s, 8);
            msum[am][r] = s;
        }
    if (c == 0) {
        #pragma unroll
        for (int am = 0; am < 4; am++)
            #pragma unroll
            for (int r = 0; r < 4; r++)
                s_red[w][am * 16 + g * 4 + r] = msum[am][r];
    }
    __syncthreads();
    if (t < 64) {
        float s = 0.f;
        #pragma unroll
        for (int ww = 0; ww < 8; ww++) s += s_red[ww][t];
        atomicAdd(&ws[OFF_ASUM + b * MM + t], s);
    }
}

// ---------------- K4: split-K partials of assignment @ values ----------------
// 512 threads, grid (64,8): slice = 256 n's; micro 8m x 4d
__global__ __launch_bounds__(512, 4) void k4_av(
    const float* __restrict__ values, float* __restrict__ ws)
{
    __shared__ float Vs[16][256];    // 16 KB
    __shared__ float Ast[16][72];    // 4.5 KB
    int t = threadIdx.x;
    int slice = blockIdx.x, b = blockIdx.y;
    int tm = t >> 6, tt = t & 63;
    const float* asnT = ws + OFF_ASNT + (size_t)b * NP * MM;
    const float* vb = values + (size_t)b * NP * DD;

    float acc[8][4];
    #pragma unroll
    for (int i = 0; i < 8; i++)
        #pragma unroll
        for (int q = 0; q < 4; q++) acc[i][q] = 0.f;

    int nbase = slice * 256;
    for (int kc = 0; kc < 16; kc++) {
        int nb = nbase + kc * 16;
        __syncthreads();
        #pragma unroll
        for (int i = 0; i < 2; i++) {
            int f = i * 512 + t;
            int kd = f >> 6, c4 = (f & 63) * 4;
            *(float4*)&Vs[kd][c4] = *(const float4*)&vb[(size_t)(nb + kd) * DD + c4];
        }
        if (t < 256) {
            int kd = t >> 4, me4 = (t & 15) * 4;
            *(float4*)&Ast[kd][me4] = *(const float4*)&asnT[(size_t)(nb + kd) * MM + me4];
        }
        __syncthreads();
        #pragma unroll
        for (int kd = 0; kd < 16; kd++) {
            float4 a0 = *(const float4*)&Ast[kd][tm * 8];
            float4 a1 = *(const float4*)&Ast[kd][tm * 8 + 4];
            float4 b0 = *(const float4*)&Vs[kd][tt * 4];
            float av[8] = {a0.x, a0.y, a0.z, a0.w, a1.x, a1.y, a1.z, a1.w};
            float bq[4] = {b0.x, b0.y, b0.z, b0.w};
            #pragma unroll
            for (int i = 0; i < 8; i++)
                #pragma unroll
                for (int q = 0; q < 4; q++) acc[i][q] += av[i] * bq[q];
        }
    }
    float* part = ws + OFF_PART + ((size_t)slice * BB + b) * MM * DD;
    #pragma unroll
    for (int i = 0; i < 8; i++) {
        int m = tm * 8 + i;
        *(float4*)&part[(size_t)m * DD + tt * 4] =
            make_float4(acc[i][0], acc[i][1], acc[i][2], acc[i][3]);
    }
}

// ---------------- K5: agg = (vc + sum_s part) / (asum + EPS) ----------------
__global__ __launch_bounds__(256) void k5_agg(float* __restrict__ ws)
{
    int bm = blockIdx.x, t = threadIdx.x;
    float r = 1.f / (ws[OFF_ASUM + bm] + EPSF);
    size_t o = (size_t)bm * DD + t;
    const float* part = ws + OFF_PART;
    float s0 = 0.f, s1 = 0.f, s2 = 0.f, s3 = 0.f;
    #pragma unroll 4
    for (int s = 0; s < 64; s += 4) {
        s0 += part[(size_t)(s + 0) * (BB * MM * DD) + o];
        s1 += part[(size_t)(s + 1) * (BB * MM * DD) + o];
        s2 += part[(size_t)(s + 2) * (BB * MM * DD) + o];
        s3 += part[(size_t)(s + 3) * (BB * MM * DD) + o];
    }
    ws[OFF_AGG + o] = (ws[OFF_VC + o] + ((s0 + s1) + (s2 + s3))) * r;
}

// ---------------- K6: x = agg^T @ assignment ----------------
// 256 threads, grid (128,4,8): tile 64d x 128n, micro 8d x 4n
__global__ __launch_bounds__(256, 3) void k6_x(
    float* __restrict__ out, const float* __restrict__ ws)
{
    __shared__ float aggs[64][68];    // 17 KB  [m][d-tile]
    __shared__ float asns[64][132];   // 33 KB  [m][n-tile]
    int t = threadIdx.x;
    int n0 = blockIdx.x * 128, d0 = blockIdx.y * 64, b = blockIdx.z;
    const float* agg = ws + OFF_AGG + (size_t)b * MM * DD;
    const float* asnT = ws + OFF_ASNT + (size_t)b * NP * MM;

    #pragma unroll
    for (int i = 0; i < 4; i++) {
        int f = i * 256 + t;
        int m = f >> 4, c4 = (f & 15) * 4;
        *(float4*)&aggs[m][c4] = *(const float4*)&agg[(size_t)m * DD + d0 + c4];
    }
    #pragma unroll
    for (int s = 0; s < 8; s++) {
        int f = s * 256 + t;
        int nr = f >> 4, fm = f & 15;
        float4 v = *(const float4*)&asnT[(size_t)(n0 + nr) * MM + fm * 4];
        asns[fm * 4 + 0][nr] = v.x; asns[fm * 4 + 1][nr] = v.y;
        asns[fm * 4 + 2][nr] = v.z; asns[fm * 4 + 3][nr] = v.w;
    }
    __syncthreads();

    int td = t >> 5, tn = t & 31;
    float acc[8][4];
    #pragma unroll
    for (int i = 0; i < 8; i++)
        #pragma unroll
        for (int q = 0; q < 4; q++) acc[i][q] = 0.f;

    #pragma unroll 8
    for (int m = 0; m < 64; m++) {
        float4 a0 = *(const float4*)&aggs[m][td * 4];
        float4 a1 = *(const float4*)&aggs[m][32 + td * 4];
        float4 b0 = *(const float4*)&asns[m][tn * 4];
        float av[8] = {a0.x, a0.y, a0.z, a0.w, a1.x, a1.y, a1.z, a1.w};
        float bq[4] = {b0.x, b0.y, b0.z, b0.w};
        #pragma unroll
        for (int i = 0; i < 8; i++)
            #pragma unroll
            for (int q = 0; q < 4; q++) acc[i][q] += av[i] * bq[q];
    }

    float* ob = out + (size_t)b * DD * NP;
    #pragma unroll
    for (int i = 0; i < 8; i++) {
        int d = d0 + ((i < 4) ? (td * 4 + i) : (32 + td * 4 + (i - 4)));
        *(float4*)&ob[(size_t)d * NP + n0 + tn * 4] =
            make_float4(acc[i][0], acc[i][1], acc[i][2], acc[i][3]);
    }
}

extern "C" void kernel_launch(void* const* d_in, const int* in_sizes, int n_in,
                              void* d_out, int out_size, void* d_ws, size_t ws_size,
                              hipStream_t stream) {
    const float* points    = (const float*)d_in[0];
    const float* clusters  = (const float*)d_in[1];
    const float* values    = (const float*)d_in[2];
    const float* vclusters = (const float*)d_in[3];
    const float* alpha     = (const float*)d_in[4];
    const float* beta      = (const float*)d_in[5];
    const float* cbias     = (const float*)d_in[6];
    const float* Wc        = (const float*)d_in[7];
    const float* bc        = (const float*)d_in[8];
    const float* vcbias    = (const float*)d_in[9];
    const float* Wv        = (const float*)d_in[10];
    const float* bvv       = (const float*)d_in[11];
    float* out = (float*)d_out;
    float* ws = (float*)d_ws;

    // zero asum only (partials are fully overwritten, agg written by k5)
    hipMemsetAsync((char*)d_ws + (size_t)OFF_ASUM * 4, 0, 512 * 4, stream);

    k0_transpose<<<dim3(8, 8, 2), 256, 0, stream>>>(Wc, Wv, ws);
    k1_prep<<<dim3(4, 8, 2), 256, 0, stream>>>(clusters, vclusters, alpha, cbias, bc, vcbias, bvv, ws);
    k3_sim<<<dim3(64, 8), 512, 0, stream>>>(points, beta, ws);
    k4_av<<<dim3(64, 8), 512, 0, stream>>>(values, ws);
    k5_agg<<<dim3(512), 256, 0, stream>>>(ws);
    k6_x<<<dim3(128, 4, 8), 256, 0, stream>>>(out, ws);
}

// Round 2
// 440.415 us; speedup vs baseline: 1.0924x; 1.0054x over previous
//
#include <hip/hip_runtime.h>
#include <math.h>

#define BB 8
#define MM 64
#define DD 256
#define NP 16384
#define EPSF 1e-7f
#define NEPS 1e-12f

// ws layout (float offsets)
#define OFF_AT   0u          // At   [B][D][M]  alpha * normalized c, transposed
#define OFF_VC   131072u     // vc   [B][M][D]
#define OFF_AGG  262144u     // agg  [B][M][D]
#define OFF_ASUM 393216u     // asum [B][M]
#define OFF_ASNT 393728u     // asnT [B][N][M]  assignment transposed
#define OFF_WCT  8782336u    // Wc^T [D][D]
#define OFF_WVT  8847872u    // Wv^T [D][D]
#define OFF_PART 8913408u    // part [64][B][M][D] split-K partials (32 MB)

typedef __attribute__((ext_vector_type(8))) short bf16x8;
typedef __attribute__((ext_vector_type(4))) float f32x4;

// ---------------- K0: transpose Wc, Wv ----------------
__global__ __launch_bounds__(256) void k0_transpose(
    const float* __restrict__ Wc, const float* __restrict__ Wv,
    float* __restrict__ ws)
{
    __shared__ float tls[32][33];
    int which = blockIdx.z;
    const float* W = which ? Wv : Wc;
    float* Wt = ws + (which ? OFF_WVT : OFF_WCT);
    int j0 = blockIdx.x * 32, k0 = blockIdx.y * 32;
    int c = threadIdx.x & 31, r0 = threadIdx.x >> 5;
    #pragma unroll
    for (int rr = r0; rr < 32; rr += 8)
        tls[rr][c] = W[(size_t)(j0 + rr) * DD + k0 + c];
    __syncthreads();
    #pragma unroll
    for (int rr = r0; rr < 32; rr += 8)
        Wt[(size_t)(k0 + rr) * DD + j0 + c] = tls[c][rr];
}

// ---------------- K1: c / vc prep ----------------
__global__ __launch_bounds__(256) void k1_prep(
    const float* __restrict__ clusters, const float* __restrict__ vclusters,
    const float* __restrict__ alpha, const float* __restrict__ cbias,
    const float* __restrict__ bc, const float* __restrict__ vcbias,
    const float* __restrict__ bvv, float* __restrict__ ws)
{
    __shared__ float s_in[16][256];
    __shared__ float wt_s[32][256];
    __shared__ float s_out[16][260];
    __shared__ float s_scale[16];

    int t = threadIdx.x;
    int mt = blockIdx.x, b = blockIdx.y, which = blockIdx.z;
    int m0 = mt * 16;
    const float* inp   = which ? vclusters : clusters;
    const float* ibias = which ? vcbias : cbias;
    const float* obias = which ? bvv : bc;
    const float* Wt = ws + (which ? OFF_WVT : OFF_WCT);

    #pragma unroll
    for (int i = 0; i < 4; i++) {
        int e = i * 1024 + t * 4;
        int r = e >> 8, c = e & 255;
        float4 a  = *(const float4*)&inp[((size_t)(b * MM + m0 + r)) * DD + c];
        float4 bb = *(const float4*)&ibias[(size_t)(m0 + r) * DD + c];
        a.x += bb.x; a.y += bb.y; a.z += bb.z; a.w += bb.w;
        *(float4*)&s_in[r][c] = a;
    }

    int tm = t >> 5, tt = t & 31;
    float acc[2][8];
    #pragma unroll
    for (int i = 0; i < 2; i++)
        #pragma unroll
        for (int q = 0; q < 8; q++) acc[i][q] = 0.f;

    for (int k0 = 0; k0 < DD; k0 += 32) {
        __syncthreads();
        #pragma unroll
        for (int i = 0; i < 8; i++) {
            int e = i * 1024 + t * 4;
            int kd = e >> 8, c = e & 255;
            *(float4*)&wt_s[kd][c] = *(const float4*)&Wt[(size_t)(k0 + kd) * DD + c];
        }
        __syncthreads();
        #pragma unroll
        for (int kd = 0; kd < 32; kd++) {
            float a0 = s_in[tm][k0 + kd];
            float a1 = s_in[tm + 8][k0 + kd];
            float4 b0 = *(const float4*)&wt_s[kd][tt * 4];
            float4 b1 = *(const float4*)&wt_s[kd][128 + tt * 4];
            float bq[8] = {b0.x, b0.y, b0.z, b0.w, b1.x, b1.y, b1.z, b1.w};
            #pragma unroll
            for (int q = 0; q < 8; q++) { acc[0][q] += a0 * bq[q]; acc[1][q] += a1 * bq[q]; }
        }
    }

    #pragma unroll
    for (int q = 0; q < 8; q++) {
        int col = (q < 4) ? (tt * 4 + q) : (128 + tt * 4 + (q - 4));
        float ob = obias[col];
        #pragma unroll
        for (int i = 0; i < 2; i++) {
            int r = tm + i * 8;
            float x = acc[i][q] + ob;
            float s = x / (1.f + __expf(-x));   // silu
            s_out[r][col] = s;
        }
    }
    __syncthreads();

    if (which == 0) {
        if (t < 16) {
            float ss = 0.f;
            for (int j = 0; j < 256; j++) { float v = s_out[t][j]; ss += v * v; }
            s_scale[t] = alpha[m0 + t] / fmaxf(sqrtf(ss), NEPS);
        }
        __syncthreads();
        float* At = ws + OFF_AT + (size_t)b * DD * MM + (size_t)t * MM + m0;
        #pragma unroll
        for (int i = 0; i < 16; i++) At[i] = s_out[i][t] * s_scale[i];
    } else {
        float* vc = ws + OFF_VC + (size_t)(b * MM + m0) * DD;
        #pragma unroll
        for (int i = 0; i < 16; i++) vc[(size_t)i * DD + t] = s_out[i][t];
    }
}

// ---------------- K3 (MFMA bf16x3): sim + softmax + asnT + asum ----------------
__global__ __launch_bounds__(512, 4) void k3_sim(
    const float* __restrict__ points, const float* __restrict__ beta,
    float* __restrict__ ws)
{
    __shared__ __align__(16) unsigned short Ah[64][264];
    __shared__ __align__(16) unsigned short Al[64][264];
    __shared__ float s_red[8][64];
    __shared__ float s_beta[64];

    int t = threadIdx.x;
    int b = blockIdx.y;
    int n0 = blockIdx.x * 256;
    int w = t >> 6;
    int l = t & 63;
    int c = l & 15;
    int g = l >> 4;

    const float* At = ws + OFF_AT + (size_t)b * DD * MM;

    if (t < 64) s_beta[t] = beta[t];

    #pragma unroll
    for (int i = 0; i < 8; i++) {
        int f = i * 512 + t;
        int d = f >> 4, m4 = (f & 15) * 4;
        float4 v = *(const float4*)&At[(size_t)d * MM + m4];
        float xs[4] = {v.x, v.y, v.z, v.w};
        #pragma unroll
        for (int j = 0; j < 4; j++) {
            unsigned u = __float_as_uint(xs[j]);
            float lof = xs[j] - __uint_as_float(u & 0xffff0000u);
            Ah[m4 + j][d] = (unsigned short)(u >> 16);
            Al[m4 + j][d] = (unsigned short)(__float_as_uint(lof) >> 16);
        }
    }
    __syncthreads();

    const float* pb = points + (size_t)b * DD * NP;
    const float* pbase = pb + n0 + w * 32 + c;

    f32x4 acc[4][2];
    #pragma unroll
    for (int am = 0; am < 4; am++)
        #pragma unroll
        for (int an = 0; an < 2; an++)
            acc[am][an] = (f32x4){0.f, 0.f, 0.f, 0.f};

    float sq[2] = {0.f, 0.f};
    float cur[2][8], nxt[2][8];

    #pragma unroll
    for (int an = 0; an < 2; an++)
        #pragma unroll
        for (int i = 0; i < 8; i++)
            cur[an][i] = pbase[(size_t)(g * 8 + i) * NP + an * 16];

    #pragma unroll
    for (int kc = 0; kc < 8; kc++) {
        if (kc < 7) {
            #pragma unroll
            for (int an = 0; an < 2; an++)
                #pragma unroll
                for (int i = 0; i < 8; i++)
                    nxt[an][i] = pbase[(size_t)((kc + 1) * 32 + g * 8 + i) * NP + an * 16];
        }
        union { bf16x8 v; unsigned u[4]; } bh[2], bl[2];
        #pragma unroll
        for (int an = 0; an < 2; an++) {
            #pragma unroll
            for (int p = 0; p < 4; p++) {
                float x0 = cur[an][2 * p], x1 = cur[an][2 * p + 1];
                unsigned u0 = __float_as_uint(x0), u1 = __float_as_uint(x1);
                float l0f = x0 - __uint_as_float(u0 & 0xffff0000u);
                float l1f = x1 - __uint_as_float(u1 & 0xffff0000u);
                bh[an].u[p] = (u0 >> 16) | (u1 & 0xffff0000u);
                bl[an].u[p] = (__float_as_uint(l0f) >> 16) | (__float_as_uint(l1f) & 0xffff0000u);
            }
            #pragma unroll
            for (int i = 0; i < 8; i++) sq[an] += cur[an][i] * cur[an][i];
        }
        #pragma unroll
        for (int am = 0; am < 4; am++) {
            bf16x8 ah = *(const bf16x8*)&Ah[am * 16 + c][kc * 32 + g * 8];
            bf16x8 al = *(const bf16x8*)&Al[am * 16 + c][kc * 32 + g * 8];
            #pragma unroll
            for (int an = 0; an < 2; an++) {
                acc[am][an] = __builtin_amdgcn_mfma_f32_16x16x32_bf16(ah, bh[an].v, acc[am][an], 0, 0, 0);
                acc[am][an] = __builtin_amdgcn_mfma_f32_16x16x32_bf16(ah, bl[an].v, acc[am][an], 0, 0, 0);
                acc[am][an] = __builtin_amdgcn_mfma_f32_16x16x32_bf16(al, bh[an].v, acc[am][an], 0, 0, 0);
            }
        }
        if (kc < 7) {
            #pragma unroll
            for (int an = 0; an < 2; an++)
                #pragma unroll
                for (int i = 0; i < 8; i++) cur[an][i] = nxt[an][i];
        }
    }

    float pinv2[2], cmax[2], csum[2];
    #pragma unroll
    for (int an = 0; an < 2; an++) {
        float s = sq[an];
        s += __shfl_xor(s, 16);
        s += __shfl_xor(s, 32);
        pinv2[an] = 1.f / fmaxf(sqrtf(s), NEPS);
        cmax[an] = -1e30f;
    }

    #pragma unroll
    for (int am = 0; am < 4; am++)
        #pragma unroll
        for (int an = 0; an < 2; an++)
            #pragma unroll
            for (int r = 0; r < 4; r++) {
                float s = acc[am][an][r] * pinv2[an] + s_beta[am * 16 + g * 4 + r];
                acc[am][an][r] = s;
                cmax[an] = fmaxf(cmax[an], s);
            }
    #pragma unroll
    for (int an = 0; an < 2; an++) {
        cmax[an] = fmaxf(cmax[an], __shfl_xor(cmax[an], 16));
        cmax[an] = fmaxf(cmax[an], __shfl_xor(cmax[an], 32));
        csum[an] = 0.f;
    }
    #pragma unroll
    for (int am = 0; am < 4; am++)
        #pragma unroll
        for (int an = 0; an < 2; an++)
            #pragma unroll
            for (int r = 0; r < 4; r++) {
                float e = __expf(acc[am][an][r] - cmax[an]);
                acc[am][an][r] = e;
                csum[an] += e;
            }
    #pragma unroll
    for (int an = 0; an < 2; an++) {
        float s = csum[an];
        s += __shfl_xor(s, 16);
        s += __shfl_xor(s, 32);
        csum[an] = 1.f / s;
    }

    float msum[4][4];
    #pragma unroll
    for (int am = 0; am < 4; am++)
        #pragma unroll
        for (int r = 0; r < 4; r++) msum[am][r] = 0.f;

    float* asnT = ws + OFF_ASNT + (size_t)b * NP * MM;
    int ncol = n0 + w * 32 + c;
    #pragma unroll
    for (int am = 0; am < 4; am++)
        #pragma unroll
        for (int an = 0; an < 2; an++)
            #pragma unroll
            for (int r = 0; r < 4; r++) {
                float v = acc[am][an][r] * csum[an];
                asnT[(size_t)(ncol + an * 16) * MM + am * 16 + g * 4 + r] = v;
                msum[am][r] += v;
            }

    #pragma unroll
    for (int am = 0; am < 4; am++)
        #pragma unroll
        for (int r = 0; r < 4; r++) {
            float s = msum[am][r];
            s += __shfl_xor(s, 1);
            s += __shfl_xor(s, 2);
            s += __shfl_xor(s, 4);
            s += __shfl_xor(s, 8);
            msum[am][r] = s;
        }
    if (c == 0) {
        #pragma unroll
        for (int am = 0; am < 4; am++)
            #pragma unroll
            for (int r = 0; r < 4; r++)
                s_red[w][am * 16 + g * 4 + r] = msum[am][r];
    }
    __syncthreads();
    if (t < 64) {
        float s = 0.f;
        #pragma unroll
        for (int ww = 0; ww < 8; ww++) s += s_red[ww][t];
        atomicAdd(&ws[OFF_ASUM + b * MM + t], s);
    }
}

// ---------------- K4 (MFMA bf16x3): split-K partials of assignment @ values ----
// 512 threads = 8 waves; wave w owns d-range [w*32, w*32+32); block: 64m x 256d,
// K = 256 n per slice. A = asn chunk hi/lo in LDS; B = values direct from global.
__global__ __launch_bounds__(512, 4) void k4_av(
    const float* __restrict__ values, float* __restrict__ ws)
{
    __shared__ __align__(16) unsigned short Ah[64][264];
    __shared__ __align__(16) unsigned short Al[64][264];

    int t = threadIdx.x;
    int slice = blockIdx.x, b = blockIdx.y;
    int w = t >> 6;
    int l = t & 63;
    int c = l & 15;
    int g = l >> 4;
    int nb = slice * 256;

    const float* asnT = ws + OFF_ASNT + (size_t)b * NP * MM;
    const float* vb = values + (size_t)b * NP * DD;

    // prologue: asn chunk [256 n][64 m] -> Ah/Al [m][n_local]
    #pragma unroll
    for (int i = 0; i < 8; i++) {
        int f = i * 512 + t;
        int n = f >> 4, m4 = (f & 15) * 4;
        float4 v = *(const float4*)&asnT[(size_t)(nb + n) * MM + m4];
        float xs[4] = {v.x, v.y, v.z, v.w};
        #pragma unroll
        for (int j = 0; j < 4; j++) {
            unsigned u = __float_as_uint(xs[j]);
            float lof = xs[j] - __uint_as_float(u & 0xffff0000u);
            Ah[m4 + j][n] = (unsigned short)(u >> 16);
            Al[m4 + j][n] = (unsigned short)(__float_as_uint(lof) >> 16);
        }
    }
    __syncthreads();

    const float* vbase = vb + (size_t)nb * DD + w * 32 + c;

    f32x4 acc[4][2];
    #pragma unroll
    for (int am = 0; am < 4; am++)
        #pragma unroll
        for (int an = 0; an < 2; an++)
            acc[am][an] = (f32x4){0.f, 0.f, 0.f, 0.f};

    float cur[2][8], nxt[2][8];
    #pragma unroll
    for (int an = 0; an < 2; an++)
        #pragma unroll
        for (int i = 0; i < 8; i++)
            cur[an][i] = vbase[(size_t)(g * 8 + i) * DD + an * 16];

    #pragma unroll
    for (int kc = 0; kc < 8; kc++) {
        if (kc < 7) {
            #pragma unroll
            for (int an = 0; an < 2; an++)
                #pragma unroll
                for (int i = 0; i < 8; i++)
                    nxt[an][i] = vbase[(size_t)((kc + 1) * 32 + g * 8 + i) * DD + an * 16];
        }
        union { bf16x8 v; unsigned u[4]; } bh[2], bl[2];
        #pragma unroll
        for (int an = 0; an < 2; an++) {
            #pragma unroll
            for (int p = 0; p < 4; p++) {
                float x0 = cur[an][2 * p], x1 = cur[an][2 * p + 1];
                unsigned u0 = __float_as_uint(x0), u1 = __float_as_uint(x1);
                float l0f = x0 - __uint_as_float(u0 & 0xffff0000u);
                float l1f = x1 - __uint_as_float(u1 & 0xffff0000u);
                bh[an].u[p] = (u0 >> 16) | (u1 & 0xffff0000u);
                bl[an].u[p] = (__float_as_uint(l0f) >> 16) | (__float_as_uint(l1f) & 0xffff0000u);
            }
        }
        #pragma unroll
        for (int am = 0; am < 4; am++) {
            bf16x8 ah = *(const bf16x8*)&Ah[am * 16 + c][kc * 32 + g * 8];
            bf16x8 al = *(const bf16x8*)&Al[am * 16 + c][kc * 32 + g * 8];
            #pragma unroll
            for (int an = 0; an < 2; an++) {
                acc[am][an] = __builtin_amdgcn_mfma_f32_16x16x32_bf16(ah, bh[an].v, acc[am][an], 0, 0, 0);
                acc[am][an] = __builtin_amdgcn_mfma_f32_16x16x32_bf16(ah, bl[an].v, acc[am][an], 0, 0, 0);
                acc[am][an] = __builtin_amdgcn_mfma_f32_16x16x32_bf16(al, bh[an].v, acc[am][an], 0, 0, 0);
            }
        }
        if (kc < 7) {
            #pragma unroll
            for (int an = 0; an < 2; an++)
                #pragma unroll
                for (int i = 0; i < 8; i++) cur[an][i] = nxt[an][i];
        }
    }

    float* part = ws + OFF_PART + ((size_t)slice * BB + b) * MM * DD;
    #pragma unroll
    for (int am = 0; am < 4; am++)
        #pragma unroll
        for (int an = 0; an < 2; an++)
            #pragma unroll
            for (int r = 0; r < 4; r++) {
                int m = am * 16 + g * 4 + r;
                part[(size_t)m * DD + w * 32 + an * 16 + c] = acc[am][an][r];
            }
}

// ---------------- K5: agg = (vc + sum_s part) / (asum + EPS) ----------------
__global__ __launch_bounds__(256) void k5_agg(float* __restrict__ ws)
{
    int bm = blockIdx.x, t = threadIdx.x;
    float r = 1.f / (ws[OFF_ASUM + bm] + EPSF);
    size_t o = (size_t)bm * DD + t;
    const float* part = ws + OFF_PART;
    float s0 = 0.f, s1 = 0.f, s2 = 0.f, s3 = 0.f;
    #pragma unroll 4
    for (int s = 0; s < 64; s += 4) {
        s0 += part[(size_t)(s + 0) * (BB * MM * DD) + o];
        s1 += part[(size_t)(s + 1) * (BB * MM * DD) + o];
        s2 += part[(size_t)(s + 2) * (BB * MM * DD) + o];
        s3 += part[(size_t)(s + 3) * (BB * MM * DD) + o];
    }
    ws[OFF_AGG + o] = (ws[OFF_VC + o] + ((s0 + s1) + (s2 + s3))) * r;
}

// ---------------- K6 (MFMA bf16x3): x = agg^T @ assignment ----------------
// 512 threads = 8 waves; wave w: d-quarter (w>>1)*64, n-half (w&1)*32.
// Block: 256d x 64n, K = m = 64. A = agg^T hi/lo in LDS; B = asnT direct global.
__global__ __launch_bounds__(512, 4) void k6_x(
    float* __restrict__ out, const float* __restrict__ ws)
{
    __shared__ __align__(16) unsigned short Ah[256][72];
    __shared__ __align__(16) unsigned short Al[256][72];

    int t = threadIdx.x;
    int n0 = blockIdx.x * 64, b = blockIdx.y;
    int w = t >> 6;
    int l = t & 63;
    int c = l & 15;
    int g = l >> 4;
    int dq = w >> 1, nh = w & 1;

    const float* agg = ws + OFF_AGG + (size_t)b * MM * DD;
    const float* asnT = ws + OFF_ASNT + (size_t)b * NP * MM;

    // prologue: agg [64 m][256 d] -> Ah/Al [d][m]
    #pragma unroll
    for (int i = 0; i < 8; i++) {
        int f = i * 512 + t;
        int m = f >> 6, d4 = (f & 63) * 4;
        float4 v = *(const float4*)&agg[(size_t)m * DD + d4];
        float xs[4] = {v.x, v.y, v.z, v.w};
        #pragma unroll
        for (int j = 0; j < 4; j++) {
            unsigned u = __float_as_uint(xs[j]);
            float lof = xs[j] - __uint_as_float(u & 0xffff0000u);
            Ah[d4 + j][m] = (unsigned short)(u >> 16);
            Al[d4 + j][m] = (unsigned short)(__float_as_uint(lof) >> 16);
        }
    }

    // B fragments (asn): lane (c,g) reads 8 contiguous m floats per (kc,an)
    union { bf16x8 v; unsigned u[4]; } bh[2][2], bl[2][2];
    #pragma unroll
    for (int kc = 0; kc < 2; kc++)
        #pragma unroll
        for (int an = 0; an < 2; an++) {
            const float* src = &asnT[(size_t)(n0 + nh * 32 + an * 16 + c) * MM + kc * 32 + g * 8];
            float4 v0 = *(const float4*)src;
            float4 v1 = *(const float4*)(src + 4);
            float xs[8] = {v0.x, v0.y, v0.z, v0.w, v1.x, v1.y, v1.z, v1.w};
            #pragma unroll
            for (int p = 0; p < 4; p++) {
                float x0 = xs[2 * p], x1 = xs[2 * p + 1];
                unsigned u0 = __float_as_uint(x0), u1 = __float_as_uint(x1);
                float l0f = x0 - __uint_as_float(u0 & 0xffff0000u);
                float l1f = x1 - __uint_as_float(u1 & 0xffff0000u);
                bh[kc][an].u[p] = (u0 >> 16) | (u1 & 0xffff0000u);
                bl[kc][an].u[p] = (__float_as_uint(l0f) >> 16) | (__float_as_uint(l1f) & 0xffff0000u);
            }
        }
    __syncthreads();

    f32x4 acc[4][2];
    #pragma unroll
    for (int am = 0; am < 4; am++)
        #pragma unroll
        for (int an = 0; an < 2; an++)
            acc[am][an] = (f32x4){0.f, 0.f, 0.f, 0.f};

    #pragma unroll
    for (int kc = 0; kc < 2; kc++)
        #pragma unroll
        for (int am = 0; am < 4; am++) {
            bf16x8 ah = *(const bf16x8*)&Ah[dq * 64 + am * 16 + c][kc * 32 + g * 8];
            bf16x8 al = *(const bf16x8*)&Al[dq * 64 + am * 16 + c][kc * 32 + g * 8];
            #pragma unroll
            for (int an = 0; an < 2; an++) {
                acc[am][an] = __builtin_amdgcn_mfma_f32_16x16x32_bf16(ah, bh[kc][an].v, acc[am][an], 0, 0, 0);
                acc[am][an] = __builtin_amdgcn_mfma_f32_16x16x32_bf16(ah, bl[kc][an].v, acc[am][an], 0, 0, 0);
                acc[am][an] = __builtin_amdgcn_mfma_f32_16x16x32_bf16(al, bh[kc][an].v, acc[am][an], 0, 0, 0);
            }
        }

    float* ob = out + (size_t)b * DD * NP;
    #pragma unroll
    for (int am = 0; am < 4; am++)
        #pragma unroll
        for (int an = 0; an < 2; an++)
            #pragma unroll
            for (int r = 0; r < 4; r++) {
                int d = dq * 64 + am * 16 + g * 4 + r;
                ob[(size_t)d * NP + n0 + nh * 32 + an * 16 + c] = acc[am][an][r];
            }
}

extern "C" void kernel_launch(void* const* d_in, const int* in_sizes, int n_in,
                              void* d_out, int out_size, void* d_ws, size_t ws_size,
                              hipStream_t stream) {
    const float* points    = (const float*)d_in[0];
    const float* clusters  = (const float*)d_in[1];
    const float* values    = (const float*)d_in[2];
    const float* vclusters = (const float*)d_in[3];
    const float* alpha     = (const float*)d_in[4];
    const float* beta      = (const float*)d_in[5];
    const float* cbias     = (const float*)d_in[6];
    const float* Wc        = (const float*)d_in[7];
    const float* bc        = (const float*)d_in[8];
    const float* vcbias    = (const float*)d_in[9];
    const float* Wv        = (const float*)d_in[10];
    const float* bvv       = (const float*)d_in[11];
    float* out = (float*)d_out;
    float* ws = (float*)d_ws;

    // zero asum only (partials are fully overwritten, agg written by k5)
    hipMemsetAsync((char*)d_ws + (size_t)OFF_ASUM * 4, 0, 512 * 4, stream);

    k0_transpose<<<dim3(8, 8, 2), 256, 0, stream>>>(Wc, Wv, ws);
    k1_prep<<<dim3(4, 8, 2), 256, 0, stream>>>(clusters, vclusters, alpha, cbias, bc, vcbias, bvv, ws);
    k3_sim<<<dim3(64, 8), 512, 0, stream>>>(points, beta, ws);
    k4_av<<<dim3(64, 8), 512, 0, stream>>>(values, ws);
    k5_agg<<<dim3(512), 256, 0, stream>>>(ws);
    k6_x<<<dim3(256, 8), 512, 0, stream>>>(out, ws);
}

// Round 3
// 413.454 us; speedup vs baseline: 1.1637x; 1.0652x over previous
//
#include <hip/hip_runtime.h>
#include <math.h>

#define BB 8
#define MM 64
#define DD 256
#define NP 16384
#define EPSF 1e-7f
#define NEPS 1e-12f

// ws layout (float offsets)
#define OFF_AT   0u          // At   [B][D][M]  alpha * normalized c, transposed
#define OFF_VC   131072u     // vc   [B][M][D]
#define OFF_AGG  262144u     // agg  [B][M][D]
#define OFF_ASUM 393216u     // asum [B][M]
#define OFF_ASNT 393728u     // asnT [B][N][M]  assignment transposed
#define OFF_WCT  8782336u    // Wc^T [D][D]
#define OFF_WVT  8847872u    // Wv^T [D][D]
#define OFF_PART 8913408u    // part [64][B][M][D] split-K partials (32 MB)

typedef __attribute__((ext_vector_type(8))) short bf16x8;
typedef __attribute__((ext_vector_type(4))) float f32x4;

// ---------------- K0: transpose Wc, Wv ----------------
__global__ __launch_bounds__(256) void k0_transpose(
    const float* __restrict__ Wc, const float* __restrict__ Wv,
    float* __restrict__ ws)
{
    __shared__ float tls[32][33];
    int which = blockIdx.z;
    const float* W = which ? Wv : Wc;
    float* Wt = ws + (which ? OFF_WVT : OFF_WCT);
    int j0 = blockIdx.x * 32, k0 = blockIdx.y * 32;
    int c = threadIdx.x & 31, r0 = threadIdx.x >> 5;
    #pragma unroll
    for (int rr = r0; rr < 32; rr += 8)
        tls[rr][c] = W[(size_t)(j0 + rr) * DD + k0 + c];
    __syncthreads();
    #pragma unroll
    for (int rr = r0; rr < 32; rr += 8)
        Wt[(size_t)(k0 + rr) * DD + j0 + c] = tls[c][rr];
}

// ---------------- K1: c / vc prep ----------------
__global__ __launch_bounds__(256) void k1_prep(
    const float* __restrict__ clusters, const float* __restrict__ vclusters,
    const float* __restrict__ alpha, const float* __restrict__ cbias,
    const float* __restrict__ bc, const float* __restrict__ vcbias,
    const float* __restrict__ bvv, float* __restrict__ ws)
{
    __shared__ float s_in[16][256];
    __shared__ float wt_s[32][256];
    __shared__ float s_out[16][260];
    __shared__ float s_scale[16];

    int t = threadIdx.x;
    int mt = blockIdx.x, b = blockIdx.y, which = blockIdx.z;
    int m0 = mt * 16;
    const float* inp   = which ? vclusters : clusters;
    const float* ibias = which ? vcbias : cbias;
    const float* obias = which ? bvv : bc;
    const float* Wt = ws + (which ? OFF_WVT : OFF_WCT);

    #pragma unroll
    for (int i = 0; i < 4; i++) {
        int e = i * 1024 + t * 4;
        int r = e >> 8, c = e & 255;
        float4 a  = *(const float4*)&inp[((size_t)(b * MM + m0 + r)) * DD + c];
        float4 bb = *(const float4*)&ibias[(size_t)(m0 + r) * DD + c];
        a.x += bb.x; a.y += bb.y; a.z += bb.z; a.w += bb.w;
        *(float4*)&s_in[r][c] = a;
    }

    int tm = t >> 5, tt = t & 31;
    float acc[2][8];
    #pragma unroll
    for (int i = 0; i < 2; i++)
        #pragma unroll
        for (int q = 0; q < 8; q++) acc[i][q] = 0.f;

    for (int k0 = 0; k0 < DD; k0 += 32) {
        __syncthreads();
        #pragma unroll
        for (int i = 0; i < 8; i++) {
            int e = i * 1024 + t * 4;
            int kd = e >> 8, c = e & 255;
            *(float4*)&wt_s[kd][c] = *(const float4*)&Wt[(size_t)(k0 + kd) * DD + c];
        }
        __syncthreads();
        #pragma unroll
        for (int kd = 0; kd < 32; kd++) {
            float a0 = s_in[tm][k0 + kd];
            float a1 = s_in[tm + 8][k0 + kd];
            float4 b0 = *(const float4*)&wt_s[kd][tt * 4];
            float4 b1 = *(const float4*)&wt_s[kd][128 + tt * 4];
            float bq[8] = {b0.x, b0.y, b0.z, b0.w, b1.x, b1.y, b1.z, b1.w};
            #pragma unroll
            for (int q = 0; q < 8; q++) { acc[0][q] += a0 * bq[q]; acc[1][q] += a1 * bq[q]; }
        }
    }

    #pragma unroll
    for (int q = 0; q < 8; q++) {
        int col = (q < 4) ? (tt * 4 + q) : (128 + tt * 4 + (q - 4));
        float ob = obias[col];
        #pragma unroll
        for (int i = 0; i < 2; i++) {
            int r = tm + i * 8;
            float x = acc[i][q] + ob;
            float s = x / (1.f + __expf(-x));   // silu
            s_out[r][col] = s;
        }
    }
    __syncthreads();

    if (which == 0) {
        if (t < 16) {
            float ss = 0.f;
            for (int j = 0; j < 256; j++) { float v = s_out[t][j]; ss += v * v; }
            s_scale[t] = alpha[m0 + t] / fmaxf(sqrtf(ss), NEPS);
        }
        __syncthreads();
        float* At = ws + OFF_AT + (size_t)b * DD * MM + (size_t)t * MM + m0;
        #pragma unroll
        for (int i = 0; i < 16; i++) At[i] = s_out[i][t] * s_scale[i];
    } else {
        float* vc = ws + OFF_VC + (size_t)(b * MM + m0) * DD;
        #pragma unroll
        for (int i = 0; i < 16; i++) vc[(size_t)i * DD + t] = s_out[i][t];
    }
}

// ---------------- K3 (MFMA bf16x3): sim + softmax + asnT + asum ----------------
// 8 waves, wave w owns 64m x 32n. A hi/lo in LDS; B (points) direct from global.
// No manual prefetch: registers kept under the 128-VGPR cap of (512,4).
__global__ __launch_bounds__(512, 4) void k3_sim(
    const float* __restrict__ points, const float* __restrict__ beta,
    float* __restrict__ ws)
{
    __shared__ __align__(16) unsigned short Ah[64][264];
    __shared__ __align__(16) unsigned short Al[64][264];
    __shared__ float s_red[8][64];
    __shared__ float s_beta[64];

    int t = threadIdx.x;
    int b = blockIdx.y;
    int n0 = blockIdx.x * 256;
    int w = t >> 6;
    int l = t & 63;
    int c = l & 15;
    int g = l >> 4;

    const float* At = ws + OFF_AT + (size_t)b * DD * MM;

    if (t < 64) s_beta[t] = beta[t];

    #pragma unroll
    for (int i = 0; i < 8; i++) {
        int f = i * 512 + t;
        int d = f >> 4, m4 = (f & 15) * 4;
        float4 v = *(const float4*)&At[(size_t)d * MM + m4];
        float xs[4] = {v.x, v.y, v.z, v.w};
        #pragma unroll
        for (int j = 0; j < 4; j++) {
            unsigned u = __float_as_uint(xs[j]);
            float lof = xs[j] - __uint_as_float(u & 0xffff0000u);
            Ah[m4 + j][d] = (unsigned short)(u >> 16);
            Al[m4 + j][d] = (unsigned short)(__float_as_uint(lof) >> 16);
        }
    }
    __syncthreads();

    const float* pb = points + (size_t)b * DD * NP;
    const float* pk = pb + n0 + w * 32 + c + (size_t)g * 8 * NP;

    f32x4 acc[4][2];
    #pragma unroll
    for (int am = 0; am < 4; am++)
        #pragma unroll
        for (int an = 0; an < 2; an++)
            acc[am][an] = (f32x4){0.f, 0.f, 0.f, 0.f};

    float sq[2] = {0.f, 0.f};

    for (int kc = 0; kc < 8; kc++) {
        float cur[2][8];
        #pragma unroll
        for (int an = 0; an < 2; an++)
            #pragma unroll
            for (int i = 0; i < 8; i++)
                cur[an][i] = pk[(size_t)i * NP + an * 16];

        union { bf16x8 v; unsigned u[4]; } bh[2], bl[2];
        #pragma unroll
        for (int an = 0; an < 2; an++) {
            #pragma unroll
            for (int p = 0; p < 4; p++) {
                float x0 = cur[an][2 * p], x1 = cur[an][2 * p + 1];
                unsigned u0 = __float_as_uint(x0), u1 = __float_as_uint(x1);
                float l0f = x0 - __uint_as_float(u0 & 0xffff0000u);
                float l1f = x1 - __uint_as_float(u1 & 0xffff0000u);
                bh[an].u[p] = (u0 >> 16) | (u1 & 0xffff0000u);
                bl[an].u[p] = (__float_as_uint(l0f) >> 16) | (__float_as_uint(l1f) & 0xffff0000u);
            }
            #pragma unroll
            for (int i = 0; i < 8; i++) sq[an] += cur[an][i] * cur[an][i];
        }
        #pragma unroll
        for (int am = 0; am < 4; am++) {
            bf16x8 ah = *(const bf16x8*)&Ah[am * 16 + c][kc * 32 + g * 8];
            bf16x8 al = *(const bf16x8*)&Al[am * 16 + c][kc * 32 + g * 8];
            #pragma unroll
            for (int an = 0; an < 2; an++) {
                acc[am][an] = __builtin_amdgcn_mfma_f32_16x16x32_bf16(ah, bh[an].v, acc[am][an], 0, 0, 0);
                acc[am][an] = __builtin_amdgcn_mfma_f32_16x16x32_bf16(ah, bl[an].v, acc[am][an], 0, 0, 0);
                acc[am][an] = __builtin_amdgcn_mfma_f32_16x16x32_bf16(al, bh[an].v, acc[am][an], 0, 0, 0);
            }
        }
        pk += 32 * NP;
    }

    float pinv2[2], cmax[2], csum[2];
    #pragma unroll
    for (int an = 0; an < 2; an++) {
        float s = sq[an];
        s += __shfl_xor(s, 16);
        s += __shfl_xor(s, 32);
        pinv2[an] = 1.f / fmaxf(sqrtf(s), NEPS);
        cmax[an] = -1e30f;
    }

    #pragma unroll
    for (int am = 0; am < 4; am++)
        #pragma unroll
        for (int an = 0; an < 2; an++)
            #pragma unroll
            for (int r = 0; r < 4; r++) {
                float s = acc[am][an][r] * pinv2[an] + s_beta[am * 16 + g * 4 + r];
                acc[am][an][r] = s;
                cmax[an] = fmaxf(cmax[an], s);
            }
    #pragma unroll
    for (int an = 0; an < 2; an++) {
        cmax[an] = fmaxf(cmax[an], __shfl_xor(cmax[an], 16));
        cmax[an] = fmaxf(cmax[an], __shfl_xor(cmax[an], 32));
        csum[an] = 0.f;
    }
    #pragma unroll
    for (int am = 0; am < 4; am++)
        #pragma unroll
        for (int an = 0; an < 2; an++)
            #pragma unroll
            for (int r = 0; r < 4; r++) {
                float e = __expf(acc[am][an][r] - cmax[an]);
                acc[am][an][r] = e;
                csum[an] += e;
            }
    #pragma unroll
    for (int an = 0; an < 2; an++) {
        float s = csum[an];
        s += __shfl_xor(s, 16);
        s += __shfl_xor(s, 32);
        csum[an] = 1.f / s;
    }

    float msum[4][4];
    #pragma unroll
    for (int am = 0; am < 4; am++)
        #pragma unroll
        for (int r = 0; r < 4; r++) msum[am][r] = 0.f;

    float* asnT = ws + OFF_ASNT + (size_t)b * NP * MM;
    int ncol = n0 + w * 32 + c;
    #pragma unroll
    for (int am = 0; am < 4; am++)
        #pragma unroll
        for (int an = 0; an < 2; an++)
            #pragma unroll
            for (int r = 0; r < 4; r++) {
                float v = acc[am][an][r] * csum[an];
                asnT[(size_t)(ncol + an * 16) * MM + am * 16 + g * 4 + r] = v;
                msum[am][r] += v;
            }

    #pragma unroll
    for (int am = 0; am < 4; am++)
        #pragma unroll
        for (int r = 0; r < 4; r++) {
            float s = msum[am][r];
            s += __shfl_xor(s, 1);
            s += __shfl_xor(s, 2);
            s += __shfl_xor(s, 4);
            s += __shfl_xor(s, 8);
            msum[am][r] = s;
        }
    if (c == 0) {
        #pragma unroll
        for (int am = 0; am < 4; am++)
            #pragma unroll
            for (int r = 0; r < 4; r++)
                s_red[w][am * 16 + g * 4 + r] = msum[am][r];
    }
    __syncthreads();
    if (t < 64) {
        float s = 0.f;
        #pragma unroll
        for (int ww = 0; ww < 8; ww++) s += s_red[ww][t];
        atomicAdd(&ws[OFF_ASUM + b * MM + t], s);
    }
}

// ---------------- K4 (MFMA bf16 single): split-K partials of asn @ values ------
// asn (in [0,1], normalized later by asum~256) and values both single-bf16:
// added error ~1.6e-5 on agg. 8 MFMA/kc, ~75 VGPR, 34 KB LDS -> 3-4 blocks/CU.
__global__ __launch_bounds__(512, 4) void k4_av(
    const float* __restrict__ values, float* __restrict__ ws)
{
    __shared__ __align__(16) unsigned short As[64][264];

    int t = threadIdx.x;
    int slice = blockIdx.x, b = blockIdx.y;
    int w = t >> 6;
    int l = t & 63;
    int c = l & 15;
    int g = l >> 4;
    int nb = slice * 256;

    const float* asnT = ws + OFF_ASNT + (size_t)b * NP * MM;
    const float* vb = values + (size_t)b * NP * DD;

    // prologue: asn chunk [256 n][64 m] -> As[m][n_local] (bf16 trunc)
    #pragma unroll
    for (int i = 0; i < 8; i++) {
        int f = i * 512 + t;
        int n = f >> 4, m4 = (f & 15) * 4;
        float4 v = *(const float4*)&asnT[(size_t)(nb + n) * MM + m4];
        As[m4 + 0][n] = (unsigned short)(__float_as_uint(v.x) >> 16);
        As[m4 + 1][n] = (unsigned short)(__float_as_uint(v.y) >> 16);
        As[m4 + 2][n] = (unsigned short)(__float_as_uint(v.z) >> 16);
        As[m4 + 3][n] = (unsigned short)(__float_as_uint(v.w) >> 16);
    }
    __syncthreads();

    const float* vk = vb + (size_t)nb * DD + w * 32 + c + (size_t)g * 8 * DD;

    f32x4 acc[4][2];
    #pragma unroll
    for (int am = 0; am < 4; am++)
        #pragma unroll
        for (int an = 0; an < 2; an++)
            acc[am][an] = (f32x4){0.f, 0.f, 0.f, 0.f};

    for (int kc = 0; kc < 8; kc++) {
        float cur[2][8];
        #pragma unroll
        for (int an = 0; an < 2; an++)
            #pragma unroll
            for (int i = 0; i < 8; i++)
                cur[an][i] = vk[(size_t)i * DD + an * 16];

        union { bf16x8 v; unsigned u[4]; } bh[2];
        #pragma unroll
        for (int an = 0; an < 2; an++)
            #pragma unroll
            for (int p = 0; p < 4; p++) {
                unsigned u0 = __float_as_uint(cur[an][2 * p]);
                unsigned u1 = __float_as_uint(cur[an][2 * p + 1]);
                bh[an].u[p] = (u0 >> 16) | (u1 & 0xffff0000u);
            }
        #pragma unroll
        for (int am = 0; am < 4; am++) {
            bf16x8 ah = *(const bf16x8*)&As[am * 16 + c][kc * 32 + g * 8];
            #pragma unroll
            for (int an = 0; an < 2; an++)
                acc[am][an] = __builtin_amdgcn_mfma_f32_16x16x32_bf16(ah, bh[an].v, acc[am][an], 0, 0, 0);
        }
        vk += 32 * DD;
    }

    float* part = ws + OFF_PART + ((size_t)slice * BB + b) * MM * DD;
    #pragma unroll
    for (int am = 0; am < 4; am++)
        #pragma unroll
        for (int an = 0; an < 2; an++)
            #pragma unroll
            for (int r = 0; r < 4; r++) {
                int m = am * 16 + g * 4 + r;
                part[(size_t)m * DD + w * 32 + an * 16 + c] = acc[am][an][r];
            }
}

// ---------------- K5: agg = (vc + sum_s part) / (asum + EPS) ----------------
__global__ __launch_bounds__(256) void k5_agg(float* __restrict__ ws)
{
    int bm = blockIdx.x, t = threadIdx.x;
    float r = 1.f / (ws[OFF_ASUM + bm] + EPSF);
    size_t o = (size_t)bm * DD + t;
    const float* part = ws + OFF_PART;
    float s0 = 0.f, s1 = 0.f, s2 = 0.f, s3 = 0.f;
    #pragma unroll 4
    for (int s = 0; s < 64; s += 4) {
        s0 += part[(size_t)(s + 0) * (BB * MM * DD) + o];
        s1 += part[(size_t)(s + 1) * (BB * MM * DD) + o];
        s2 += part[(size_t)(s + 2) * (BB * MM * DD) + o];
        s3 += part[(size_t)(s + 3) * (BB * MM * DD) + o];
    }
    ws[OFF_AGG + o] = (ws[OFF_VC + o] + ((s0 + s1) + (s2 + s3))) * r;
}

// ---------------- K6 (MFMA bf16 single): x = agg^T @ assignment ----------------
// 512 threads = 8 waves; wave w: d-quarter (w>>1)*64, n-half (w&1)*32.
// Block: 256d x 64n, K = m = 64. Single-bf16 agg and asn: added err ~2e-5.
__global__ __launch_bounds__(512, 4) void k6_x(
    float* __restrict__ out, const float* __restrict__ ws)
{
    __shared__ __align__(16) unsigned short Ah[256][72];

    int t = threadIdx.x;
    int n0 = blockIdx.x * 64, b = blockIdx.y;
    int w = t >> 6;
    int l = t & 63;
    int c = l & 15;
    int g = l >> 4;
    int dq = w >> 1, nh = w & 1;

    const float* agg = ws + OFF_AGG + (size_t)b * MM * DD;
    const float* asnT = ws + OFF_ASNT + (size_t)b * NP * MM;

    // prologue: agg [64 m][256 d] -> Ah[d][m] (bf16 trunc)
    #pragma unroll
    for (int i = 0; i < 8; i++) {
        int f = i * 512 + t;
        int m = f >> 6, d4 = (f & 63) * 4;
        float4 v = *(const float4*)&agg[(size_t)m * DD + d4];
        Ah[d4 + 0][m] = (unsigned short)(__float_as_uint(v.x) >> 16);
        Ah[d4 + 1][m] = (unsigned short)(__float_as_uint(v.y) >> 16);
        Ah[d4 + 2][m] = (unsigned short)(__float_as_uint(v.z) >> 16);
        Ah[d4 + 3][m] = (unsigned short)(__float_as_uint(v.w) >> 16);
    }

    // B fragments (asn): lane (c,g) reads 8 contiguous m floats per (kc,an)
    union { bf16x8 v; unsigned u[4]; } bh[2][2];
    #pragma unroll
    for (int kc = 0; kc < 2; kc++)
        #pragma unroll
        for (int an = 0; an < 2; an++) {
            const float* src = &asnT[(size_t)(n0 + nh * 32 + an * 16 + c) * MM + kc * 32 + g * 8];
            float4 v0 = *(const float4*)src;
            float4 v1 = *(const float4*)(src + 4);
            float xs[8] = {v0.x, v0.y, v0.z, v0.w, v1.x, v1.y, v1.z, v1.w};
            #pragma unroll
            for (int p = 0; p < 4; p++) {
                unsigned u0 = __float_as_uint(xs[2 * p]);
                unsigned u1 = __float_as_uint(xs[2 * p + 1]);
                bh[kc][an].u[p] = (u0 >> 16) | (u1 & 0xffff0000u);
            }
        }
    __syncthreads();

    f32x4 acc[4][2];
    #pragma unroll
    for (int am = 0; am < 4; am++)
        #pragma unroll
        for (int an = 0; an < 2; an++)
            acc[am][an] = (f32x4){0.f, 0.f, 0.f, 0.f};

    #pragma unroll
    for (int kc = 0; kc < 2; kc++)
        #pragma unroll
        for (int am = 0; am < 4; am++) {
            bf16x8 ah = *(const bf16x8*)&Ah[dq * 64 + am * 16 + c][kc * 32 + g * 8];
            #pragma unroll
            for (int an = 0; an < 2; an++)
                acc[am][an] = __builtin_amdgcn_mfma_f32_16x16x32_bf16(ah, bh[kc][an].v, acc[am][an], 0, 0, 0);
        }

    float* ob = out + (size_t)b * DD * NP;
    #pragma unroll
    for (int am = 0; am < 4; am++)
        #pragma unroll
        for (int an = 0; an < 2; an++)
            #pragma unroll
            for (int r = 0; r < 4; r++) {
                int d = dq * 64 + am * 16 + g * 4 + r;
                ob[(size_t)d * NP + n0 + nh * 32 + an * 16 + c] = acc[am][an][r];
            }
}

extern "C" void kernel_launch(void* const* d_in, const int* in_sizes, int n_in,
                              void* d_out, int out_size, void* d_ws, size_t ws_size,
                              hipStream_t stream) {
    const float* points    = (const float*)d_in[0];
    const float* clusters  = (const float*)d_in[1];
    const float* values    = (const float*)d_in[2];
    const float* vclusters = (const float*)d_in[3];
    const float* alpha     = (const float*)d_in[4];
    const float* beta      = (const float*)d_in[5];
    const float* cbias     = (const float*)d_in[6];
    const float* Wc        = (const float*)d_in[7];
    const float* bc        = (const float*)d_in[8];
    const float* vcbias    = (const float*)d_in[9];
    const float* Wv        = (const float*)d_in[10];
    const float* bvv       = (const float*)d_in[11];
    float* out = (float*)d_out;
    float* ws = (float*)d_ws;

    // zero asum only (partials are fully overwritten, agg written by k5)
    hipMemsetAsync((char*)d_ws + (size_t)OFF_ASUM * 4, 0, 512 * 4, stream);

    k0_transpose<<<dim3(8, 8, 2), 256, 0, stream>>>(Wc, Wv, ws);
    k1_prep<<<dim3(4, 8, 2), 256, 0, stream>>>(clusters, vclusters, alpha, cbias, bc, vcbias, bvv, ws);
    k3_sim<<<dim3(64, 8), 512, 0, stream>>>(points, beta, ws);
    k4_av<<<dim3(64, 8), 512, 0, stream>>>(values, ws);
    k5_agg<<<dim3(512), 256, 0, stream>>>(ws);
    k6_x<<<dim3(256, 8), 512, 0, stream>>>(out, ws);
}